// Round 4
// baseline (548.891 us; speedup 1.0000x reference)
//
#include <hip/hip_runtime.h>
#include <hip/hip_bf16.h>

// HiPPO-LegT parallel chunked scan, round 4.
// Regular launches (cooperative launch failed in-harness). Fusions:
//  - init kernel copies A->P1 and B->Kv0 (no memcpy)
//  - doubling round t: P_{m+j}=P_m@P_j (16m blocks) AND Kv_{m+j}=P_m@Kv_j (m blocks)
//  - scan round r: scan (256 blocks) AND M_{r+1}=M_r^2 (16 blocks), r<5
//  - one build kernel emits both Ht and Gt
//  - out_gemm epilogue: per-wave LDS transpose -> full-cacheline float4 stores
//
// ws layout (floats):
//   P   : A^1..A^64          (64 * 65536)
//   Kv  : A^j B, j=0..63     (64 * 256)
//   e   : scan buffer 0      (64 * 256 * 64)
//   w2  : scan buffer 1      (64 * 256 * 64)
//   MS  : squaring ping-pong (2 * 65536)
//   Ht  : bf16 [4096][640]   (hi 0..319 | lo 320..639)   (ushort)
//   Gt  : bf16 [16384][640]                               (ushort)

#define MATF 65536

typedef __attribute__((ext_vector_type(8))) short short8;
typedef __attribute__((ext_vector_type(4))) float f32x4;

__device__ __forceinline__ unsigned short f2bf(float x) {
  union { __hip_bfloat16 h; unsigned short u; } cv;
  cv.h = __float2bfloat16(x);
  return cv.u;
}
__device__ __forceinline__ float bf2f(unsigned short u) {
  union { unsigned short u; __hip_bfloat16 h; } cv;
  cv.u = u;
  return __bfloat162float(cv.h);
}

__device__ __forceinline__ void load16_lds(const void* gsrc, void* ldst) {
  __builtin_amdgcn_global_load_lds(
      (const __attribute__((address_space(1))) unsigned int*)gsrc,
      (__attribute__((address_space(3))) unsigned int*)ldst,
      16, 0, 0);
}

// 64x64 tile of a 256x256x256 fp32 product Z = X @ Y; 256 threads.
__device__ void tile_gemm64(const float* __restrict__ X,
                            const float* __restrict__ Y,
                            float* __restrict__ Z, int tile,
                            float* As, float* Bs, int tid)
{
  int tr = (tile >> 2) * 64;
  int tc = (tile & 3) * 64;
  int tx = tid & 15, ty = tid >> 4;
  float acc[4][4] = {};
  for (int k0 = 0; k0 < 256; k0 += 32) {
#pragma unroll
    for (int p = 0; p < 2; ++p) {
      int idx = tid + p * 256;
      int r = idx >> 3, c4 = (idx & 7) * 4;
      float4 v = *(const float4*)(X + (size_t)(tr + r) * 256 + k0 + c4);
      As[r * 33 + c4 + 0] = v.x; As[r * 33 + c4 + 1] = v.y;
      As[r * 33 + c4 + 2] = v.z; As[r * 33 + c4 + 3] = v.w;
    }
#pragma unroll
    for (int p = 0; p < 2; ++p) {
      int idx = tid + p * 256;
      int r = idx >> 4, c4 = (idx & 15) * 4;
      float4 v = *(const float4*)(Y + (size_t)(k0 + r) * 256 + tc + c4);
      Bs[r * 65 + c4 + 0] = v.x; Bs[r * 65 + c4 + 1] = v.y;
      Bs[r * 65 + c4 + 2] = v.z; Bs[r * 65 + c4 + 3] = v.w;
    }
    __syncthreads();
#pragma unroll
    for (int kk = 0; kk < 32; ++kk) {
      float a[4], b[4];
#pragma unroll
      for (int u = 0; u < 4; ++u) a[u] = As[(ty * 4 + u) * 33 + kk];
#pragma unroll
      for (int v = 0; v < 4; ++v) b[v] = Bs[kk * 65 + tx * 4 + v];
#pragma unroll
      for (int u = 0; u < 4; ++u)
#pragma unroll
        for (int v = 0; v < 4; ++v) acc[u][v] += a[u] * b[v];
    }
    __syncthreads();
  }
#pragma unroll
  for (int u = 0; u < 4; ++u)
#pragma unroll
    for (int v = 0; v < 4; ++v)
      Z[(size_t)(tr + ty * 4 + u) * 256 + tc + tx * 4 + v] = acc[u][v];
}

// ---------- init: P_1 = A ; Kv_0 = B ----------
__global__ __launch_bounds__(256) void init_kernel(
    const float* __restrict__ A, const float* __restrict__ Bv,
    float* __restrict__ P, float* __restrict__ Kv)
{
  int bid = blockIdx.x, tid = threadIdx.x;
  if (bid < 64) {
    int idx = bid * 256 + tid;
    *(float4*)(P + (size_t)idx * 4) = *(const float4*)(A + (size_t)idx * 4);
  } else {
    Kv[tid] = Bv[tid];
  }
}

// ---------- doubling round: P_{m+j} = P_m @ P_j ; Kv_{m+jj} = P_m @ Kv_jj ----------
__global__ __launch_bounds__(256) void pow_round(
    float* __restrict__ P, float* __restrict__ Kv, int m)
{
  __shared__ float As[64 * 33];
  __shared__ float Bs[32 * 65];
  int bid = blockIdx.x, tid = threadIdx.x;
  if (bid < m * 16) {
    int j = (bid >> 4) + 1;
    tile_gemm64(P + (size_t)(m - 1) * MATF, P + (size_t)(j - 1) * MATF,
                P + (size_t)(m + j - 1) * MATF, bid & 15, As, Bs, tid);
  } else {
    int jj = bid - m * 16;
    Bs[tid] = Kv[(size_t)jj * 256 + tid];
    __syncthreads();
    const float* Pm = P + (size_t)(m - 1) * MATF;
    float acc = 0.f;
    for (int mm = 0; mm < 256; ++mm)
      acc += Pm[(size_t)tid * 256 + mm] * Bs[mm];
    Kv[(size_t)(m + jj) * 256 + tid] = acc;
  }
}

// ---------- e phase: e_k[n][b] = sum_j Kv_j[n] * f[k*64+63-j][b] ----------
__global__ __launch_bounds__(256) void e_kernel(
    const float* __restrict__ in, const float* __restrict__ Kv,
    float* __restrict__ e)
{
  __shared__ float fs[1024];
  int bid = blockIdx.x, tid = threadIdx.x;
  int k = bid >> 2, bq = bid & 3;
#pragma unroll
  for (int q = 0; q < 4; ++q) {
    int idx = tid + q * 256;
    int i = idx >> 4, bb = idx & 15;
    fs[i * 16 + bb] = in[(size_t)(k * 64 + i) * 64 + bq * 16 + bb];
  }
  __syncthreads();
  int n = tid;
  float acc[16] = {};
  for (int j = 0; j < 64; ++j) {
    float kvj = Kv[(size_t)j * 256 + n];
#pragma unroll
    for (int b2 = 0; b2 < 16; ++b2)
      acc[b2] += kvj * fs[(63 - j) * 16 + b2];
  }
#pragma unroll
  for (int b2 = 0; b2 < 16; ++b2)
    e[((size_t)k * 256 + n) * 64 + bq * 16 + b2] = acc[b2];
}

// ---------- scan round + fused squaring ----------
// blocks 0..255: dst[k] = src[k] + M @ src[k-d] ; blocks 256..271: MSdst = M @ M
__global__ __launch_bounds__(256) void scan_round(
    const float* __restrict__ M, float* __restrict__ MSdst,
    const float* __restrict__ src_base, float* __restrict__ dst_base, int d)
{
  __shared__ float As[64 * 33];
  __shared__ float Bs[32 * 65];
  int bid = blockIdx.x, tid = threadIdx.x;
  if (bid >= 256) {
    tile_gemm64(M, M, MSdst, bid - 256, As, Bs, tid);
    return;
  }
  int k = bid >> 2, rt = bid & 3;
  const float* src = src_base + (size_t)k * 16384;
  float*       dst = dst_base + (size_t)k * 16384;
  if (k < d) {
#pragma unroll
    for (int p = 0; p < 16; ++p) {
      int idx = rt * 4096 + p * 256 + tid;
      dst[idx] = src[idx];
    }
    return;
  }
  const float* v = src_base + (size_t)(k - d) * 16384;
  int tx = tid & 15, ty = tid >> 4;
  float acc[4][4] = {};
  for (int k0 = 0; k0 < 256; k0 += 32) {
#pragma unroll
    for (int p = 0; p < 2; ++p) {
      int idx = tid + p * 256;
      int r = idx >> 3, c4 = (idx & 7) * 4;
      float4 t4 = *(const float4*)(M + (size_t)(rt * 64 + r) * 256 + k0 + c4);
      As[r * 33 + c4 + 0] = t4.x; As[r * 33 + c4 + 1] = t4.y;
      As[r * 33 + c4 + 2] = t4.z; As[r * 33 + c4 + 3] = t4.w;
    }
#pragma unroll
    for (int p = 0; p < 2; ++p) {
      int idx = tid + p * 256;
      int r = idx >> 4, c4 = (idx & 15) * 4;
      float4 t4 = *(const float4*)(v + (size_t)(k0 + r) * 64 + c4);
      Bs[r * 65 + c4 + 0] = t4.x; Bs[r * 65 + c4 + 1] = t4.y;
      Bs[r * 65 + c4 + 2] = t4.z; Bs[r * 65 + c4 + 3] = t4.w;
    }
    __syncthreads();
#pragma unroll
    for (int kk = 0; kk < 32; ++kk) {
      float a[4], b[4];
#pragma unroll
      for (int u = 0; u < 4; ++u) a[u] = As[(ty * 4 + u) * 33 + kk];
#pragma unroll
      for (int v2 = 0; v2 < 4; ++v2) b[v2] = Bs[kk * 65 + tx * 4 + v2];
#pragma unroll
      for (int u = 0; u < 4; ++u)
#pragma unroll
        for (int v2 = 0; v2 < 4; ++v2) acc[u][v2] += a[u] * b[v2];
    }
    __syncthreads();
  }
#pragma unroll
  for (int u = 0; u < 4; ++u)
#pragma unroll
    for (int v2 = 0; v2 < 4; ++v2) {
      int idx = (rt * 64 + ty * 4 + u) * 64 + tx * 4 + v2;
      dst[idx] = src[idx] + acc[u][v2];
    }
}

// ---------- build Ht (rows 0..4095) and Gt (rows 4096..20479) ----------
__global__ __launch_bounds__(320) void build_hg(
    const float* __restrict__ in, const float* __restrict__ w0,
    const float* __restrict__ Kv, const float* __restrict__ P,
    unsigned short* __restrict__ Ht, unsigned short* __restrict__ Gt)
{
  int row = blockIdx.x;
  int j = threadIdx.x;
  float x;
  unsigned short* dst;
  if (row < 4096) {
    int k = row >> 6, b = row & 63;
    if (j < 64) x = in[(size_t)(k * 64 + j) * 64 + b];
    else        x = (k > 0) ? w0[((size_t)(k - 1) * 256 + (j - 64)) * 64 + b] : 0.f;
    dst = Ht + (size_t)row * 640;
  } else {
    int r2 = row - 4096;
    int i = r2 >> 8, n = r2 & 255;
    if (j < 64) x = (j <= i) ? Kv[(size_t)(i - j) * 256 + n] : 0.f;
    else        x = P[(size_t)r2 * 256 + (j - 64)];
    dst = Gt + (size_t)r2 * 640;
  }
  unsigned short hi = f2bf(x);
  float lo = x - bf2f(hi);
  dst[j]       = hi;
  dst[320 + j] = f2bf(lo);
}

// ---------- out = Ht @ Gt^T via split-bf16 MFMA ----------
__global__ __launch_bounds__(256) void out_gemm(
    const unsigned short* __restrict__ Ht,
    const unsigned short* __restrict__ Gt,
    float* __restrict__ out)
{
  __shared__ char smem[32768];
  char* Ab = smem;
  char* Bb = smem + 16384;

  int bid = blockIdx.x;
  int swz = (bid & 7) * 512 + (bid >> 3);   // XCD swizzle (4096 % 8 == 0)
  int nt = swz >> 5;
  int mt = swz & 31;
  int mrow0 = mt * 128, nrow0 = nt * 128;

  int tid = threadIdx.x;
  int w = tid >> 6, l = tid & 63;
  int wm = w >> 1, wn = w & 1;

  auto stage = [&](const unsigned short* src, int row0, char* lds, int k0) {
#pragma unroll
    for (int it = 0; it < 4; ++it) {
      int L = it * 4096 + tid * 16;
      int row = L >> 7;
      int p = (L >> 4) & 7;
      int o = p ^ (row & 7);
      int h = o >> 2, q = o & 3;
      const void* g = src + (size_t)(row0 + row) * 640 + h * 320 + k0 + q * 8;
      void* dst = lds + (it * 4096 + w * 1024);
      load16_lds(g, dst);
    }
  };

  stage(Ht, mrow0, Ab, 0);
  stage(Gt, nrow0, Bb, 0);

  f32x4 acc[4][4] = {};
  int rAbase = wm * 64 + (l & 15);
  int rBbase = wn * 64 + (l & 15);
  int qo = l >> 4;

  for (int ks = 0; ks < 10; ++ks) {
    __syncthreads();
    short8 ah[4], al[4], bh[4], bl[4];
#pragma unroll
    for (int mf = 0; mf < 4; ++mf) {
      int r = rAbase + mf * 16;
      int ph = (qo)     ^ (r & 7);
      int pl = (4 + qo) ^ (r & 7);
      ah[mf] = *(const short8*)(Ab + r * 128 + ph * 16);
      al[mf] = *(const short8*)(Ab + r * 128 + pl * 16);
    }
#pragma unroll
    for (int nf = 0; nf < 4; ++nf) {
      int r = rBbase + nf * 16;
      int ph = (qo)     ^ (r & 7);
      int pl = (4 + qo) ^ (r & 7);
      bh[nf] = *(const short8*)(Bb + r * 128 + ph * 16);
      bl[nf] = *(const short8*)(Bb + r * 128 + pl * 16);
    }
    __syncthreads();
    if (ks < 9) {
      stage(Ht, mrow0, Ab, (ks + 1) * 32);
      stage(Gt, nrow0, Bb, (ks + 1) * 32);
    }
#pragma unroll
    for (int mf = 0; mf < 4; ++mf)
#pragma unroll
      for (int nf = 0; nf < 4; ++nf) {
        acc[mf][nf] = __builtin_amdgcn_mfma_f32_16x16x32_bf16(ah[mf], bh[nf], acc[mf][nf], 0, 0, 0);
        acc[mf][nf] = __builtin_amdgcn_mfma_f32_16x16x32_bf16(ah[mf], bl[nf], acc[mf][nf], 0, 0, 0);
        acc[mf][nf] = __builtin_amdgcn_mfma_f32_16x16x32_bf16(al[mf], bh[nf], acc[mf][nf], 0, 0, 0);
      }
  }

  // Epilogue: per-wave LDS transpose (reuse smem; per-wave region; wave-
  // internal DS ordering needs no barrier) -> 256B-contiguous float4 stores
  // (full 128B cachelines; avoids TCC write-allocate fetches).
  float* Tw = (float*)(smem + w * 4352);   // 16 rows x 68 floats
  int Mwave = mrow0 + wm * 64;
  int ncol0 = nrow0 + wn * 64;             // 64-aligned -> single i block
  int i  = ncol0 >> 8;
  int n0 = ncol0 & 255;
#pragma unroll
  for (int mf = 0; mf < 4; ++mf) {
#pragma unroll
    for (int nf = 0; nf < 4; ++nf)
#pragma unroll
      for (int r = 0; r < 4; ++r)
        Tw[((l >> 4) * 4 + r) * 68 + nf * 16 + (l & 15)] = acc[mf][nf][r];
#pragma unroll
    for (int rr = 0; rr < 4; ++rr) {
      int row16 = rr * 4 + (l >> 4);
      float4 v = *(const float4*)&Tw[row16 * 68 + (l & 15) * 4];
      int Mrow = Mwave + mf * 16 + row16;
      int k = Mrow >> 6, b = Mrow & 63;
      *(float4*)&out[((size_t)k * 4096 + (size_t)i * 64 + b) * 256 + n0 + (l & 15) * 4] = v;
    }
  }
}

extern "C" void kernel_launch(void* const* d_in, const int* in_sizes, int n_in,
                              void* d_out, int out_size, void* d_ws, size_t ws_size,
                              hipStream_t stream)
{
  const float* in = (const float*)d_in[0];
  const float* A  = (const float*)d_in[1];
  const float* Bv = (const float*)d_in[2];
  float* out = (float*)d_out;
  float* ws  = (float*)d_ws;

  float* P  = ws;                          // A^1..A^64
  float* Kv = P  + (size_t)64 * MATF;
  float* e  = Kv + (size_t)64 * 256;       // scan buf 0
  float* w2 = e  + (size_t)64 * 16384;     // scan buf 1
  float* MS = w2 + (size_t)64 * 16384;     // squaring ping-pong
  unsigned short* Ht = (unsigned short*)(MS + (size_t)2 * MATF);
  unsigned short* Gt = Ht + (size_t)4096 * 640;

  init_kernel<<<dim3(65), dim3(256), 0, stream>>>(A, Bv, P, Kv);

  for (int t = 0; t < 6; ++t) {
    int m = 1 << t;
    pow_round<<<dim3(m * 17), dim3(256), 0, stream>>>(P, Kv, m);
  }

  e_kernel<<<dim3(256), dim3(256), 0, stream>>>(in, Kv, e);

  float* bufs[2] = {e, w2};
  for (int r = 0; r < 6; ++r) {
    const float* M = (r == 0) ? (P + (size_t)63 * MATF)
                              : (MS + (size_t)((r - 1) & 1) * MATF);
    float* MSdst = MS + (size_t)(r & 1) * MATF;
    int grid = (r < 5) ? 272 : 256;
    scan_round<<<dim3(grid), dim3(256), 0, stream>>>(
        M, MSdst, bufs[r & 1], bufs[(r + 1) & 1], 1 << r);
  }
  // final scan result in e (round 5 writes bufs[0])

  build_hg<<<dim3(20480), dim3(320), 0, stream>>>(in, e, Kv, P, Ht, Gt);

  out_gemm<<<dim3(4096), dim3(256), 0, stream>>>(Ht, Gt, out);
}